// Round 4
// baseline (552.279 us; speedup 1.0000x reference)
//
#include <hip/hip_runtime.h>
#include <hip/hip_fp16.h>
#include <cstdint>
#include <cstddef>

#define B_  32
#define N_  512
#define T_  24
#define F_  64
#define FA_ 74
#define NC  1536   // T_*F_ columns per node-row

typedef __attribute__((ext_vector_type(8))) _Float16 half8;
typedef __attribute__((ext_vector_type(8))) unsigned short ushort8;
typedef __attribute__((ext_vector_type(4))) float floatx4;

// ws float layout:
//  [0,74)               rsW (rowsum of W)
//  [128,704)            W2 (symmetric, row-major 24x24)
//  [1536,132608)        adjH f16[512*512]  = 0.125*sig(alpha_i)*adj[i][k]
//  [132608,12715520)    xT  f16[b][c][k]   (32*1536*512)  ~48 MB
//  [12715520,25298432)  E0  f16[b][k][c]   (32*512*1536)  ~48 MB
#define WS_ADJ 1536
#define WS_XT  132608
#define WS_E0  12715520

#define AS1(p) ((const __attribute__((address_space(1))) void*)(p))
#define AS3(p) ((__attribute__((address_space(3))) void*)(p))

union h2u { _Float16 h; unsigned short u; };

// blocks 0..255: adj fp32 -> f16 scaled by 0.125*sigmoid(alpha_i);
// block 256: rsW + W2 param precompute.
__global__ __launch_bounds__(256) void pk_kernel(
    const float* __restrict__ adj, const float* __restrict__ alpha,
    const float* __restrict__ w, const float* __restrict__ d,
    const float* __restrict__ w2, const float* __restrict__ d2,
    float* __restrict__ ws) {
  int bid = blockIdx.x;
  int tid = threadIdx.x;
  if (bid < 256) {
    _Float16* adjH = (_Float16*)(ws + WS_ADJ);
    int g = (bid * 256 + tid) * 4;
    int row = g >> 9;
    float sc = 0.125f / (1.f + __expf(-alpha[row]));
    float4 v = *(const float4*)&adj[g];
    ushort4 u4; h2u cv;
    cv.h = (_Float16)(sc * v.x); u4.x = cv.u;
    cv.h = (_Float16)(sc * v.y); u4.y = cv.u;
    cv.h = (_Float16)(sc * v.z); u4.z = cv.u;
    cv.h = (_Float16)(sc * v.w); u4.w = cv.u;
    *(ushort4*)&adjH[g] = u4;
  } else {
    __shared__ float cs[FA_];
    if (tid < FA_) {
      float s = 0.f;
      for (int n = 0; n < FA_; ++n) s += w[n * FA_ + tid];
      cs[tid] = s;
    }
    __syncthreads();
    if (tid < FA_) {
      float s = 0.f;
      for (int p = 0; p < FA_; ++p) {
        float dc = fminf(fmaxf(d[p], 0.f), 1.f);
        s += w[tid * FA_ + p] * dc * cs[p];
      }
      ws[tid] = s;
    }
    for (int e = tid; e < T_ * T_; e += 256) {
      int a = e / T_, b = e % T_;
      float s = 0.f;
      for (int p = 0; p < T_; ++p) {
        float dc = fminf(fmaxf(d2[p], 0.f), 1.f);
        s += w2[a * T_ + p] * dc * w2[b * T_ + p];
      }
      ws[128 + e] = s;
    }
  }
}

// Fused prep: reads x ONCE. Per block: 64 k-rows x full 1536 c, in two
// 32-row passes. Per pass: load fp32 -> f16 LDS; write xT (transpose);
// compute E in-place; flush E0 + aug channels. grid (8, 32).
#define PITCH 1540   // f16 pitch: 3080 B/row (8B aligned, 2-way-max banks)
__global__ __launch_bounds__(256) void prep_kernel(
    const float* __restrict__ x, float* __restrict__ ws, float* __restrict__ out) {
  __shared__ _Float16 xs[32 * PITCH];   // 98560 B
  __shared__ float Ss[32 * 24];         // 3072 B
  _Float16* xT = (_Float16*)(ws + WS_XT);
  _Float16* E0 = (_Float16*)(ws + WS_E0);
  const float* __restrict__ W2p = ws + 128;
  int tid = threadIdx.x;
  int b = blockIdx.y;
  int k0 = blockIdx.x * 64;
  int slot = tid >> 6, f = tid & 63;
  float rsWf = ws[f];

  for (int p = 0; p < 2; ++p) {
    int r0 = k0 + p * 32;
    const float* xb = x + ((size_t)b * N_ + r0) * NC;
    // load 32x1536 fp32, cvt, stage f16: 12288 float4 = 48/thread
#pragma unroll
    for (int it = 0; it < 48; ++it) {
      int g = it * 256 + tid;
      int row = g / 384;
      int u = g - row * 384;
      float4 v = *(const float4*)&xb[(size_t)row * NC + u * 4];
      ushort4 u4; h2u cv;
      cv.h = (_Float16)v.x; u4.x = cv.u;
      cv.h = (_Float16)v.y; u4.y = cv.u;
      cv.h = (_Float16)v.z; u4.z = cv.u;
      cv.h = (_Float16)v.w; u4.w = cv.u;
      *(ushort4*)&xs[row * PITCH + u * 4] = u4;
    }
    __syncthreads();

    // xT: per it, 64 c x 32 k. lane = (q, c): q gathers k = q*8..q*8+7
#pragma unroll
    for (int it = 0; it < 24; ++it) {
      int c = it * 64 + (tid >> 2);
      int q = tid & 3;
      ushort8 v8; h2u cv;
#pragma unroll
      for (int j = 0; j < 8; ++j) {
        cv.h = xs[(q * 8 + j) * PITCH + c];
        v8[j] = cv.u;
      }
      *(ushort8*)&xT[((size_t)b * NC + c) * 512 + r0 + q * 8] = v8;
    }
    __syncthreads();

    // E in-place: thread (slot,f) owns column f of rows slot,slot+4,...
#pragma unroll
    for (int nd = 0; nd < 8; ++nd) {
      int row = nd * 4 + slot;
      float xcol[24];
#pragma unroll
      for (int t = 0; t < 24; ++t) xcol[t] = (float)xs[row * PITCH + t * 64 + f];
      float S[24];
#pragma unroll
      for (int t = 0; t < 24; ++t) S[t] = xcol[t];
#pragma unroll
      for (int off = 32; off >= 1; off >>= 1) {
#pragma unroll
        for (int t = 0; t < 24; ++t) S[t] += __shfl_xor(S[t], off, 64);
      }
      if (f == 0) {
#pragma unroll
        for (int t = 0; t < 24; ++t) Ss[row * 24 + t] = S[t];
      }
#pragma unroll
      for (int t = 0; t < 24; ++t) {
        float a = 0.f;
#pragma unroll
        for (int tp = 0; tp < 24; ++tp) a += xcol[tp] * W2p[t * 24 + tp];
        float val = 0.5f * xcol[t] + 0.25f * S[t] * rsWf + 0.25f * a;
        h2u cv; cv.h = (_Float16)val;
        xs[row * PITCH + t * 64 + f] = cv.h;
      }
    }
    __syncthreads();

    // flush E0: 32 rows x 1536 f16 = 6144 x 16B chunks = 24/thread, coalesced
    // (192 ushort8-chunks per row — NOT 96; that was round 3's coverage bug)
#pragma unroll
    for (int it = 0; it < 24; ++it) {
      int g = it * 256 + tid;
      int row = g / 192;
      int u = g - row * 192;
      ushort8 v8 = *(const ushort8*)&xs[row * PITCH + u * 8];
      *(ushort8*)&E0[((size_t)b * N_ + r0 + row) * NC + u * 8] = v8;
    }
    // aug channels: 32 rows * 24 t * 10 m = 7680 = 30/thread
#pragma unroll
    for (int it = 0; it < 30; ++it) {
      int e = it * 256 + tid;
      int row = e / 240;
      int rem = e - row * 240;
      int t = rem / 10;
      int m = rem - t * 10;
      float val = 0.25f * Ss[row * 24 + t] * ws[64 + m];
      size_t o = (((size_t)b * N_ + r0 + row) * T_ + t) * FA_ + 64 + m;
      out[o] = fmaxf(val, 0.f);
    }
    __syncthreads();
  }
}

// MFMA GEMM: acc = (0.125*sig(a)*adj) @ x ; out = relu(acc + E0) write-once.
// 128x128 tile, K=512, BK=64 (XOR-swizzled LDS), XCD-chunked block swizzle.
// grid 1536 (= 4 i x 12 c x 32 b), 256 thr.
__global__ __launch_bounds__(256) void gemm_kernel(
    const float* __restrict__ ws, float* __restrict__ out) {
  const _Float16* adjH = (const _Float16*)(ws + WS_ADJ);
  const _Float16* xT   = (const _Float16*)(ws + WS_XT);
  const _Float16* E0   = (const _Float16*)(ws + WS_E0);

  __shared__ __align__(16) char smem[50176];
  _Float16* As = (_Float16*)smem;
  _Float16* Bs = (_Float16*)(smem + 16384);
  float* accS = (float*)smem;
  _Float16* Es = (_Float16*)(smem + 33792);

  // XCD-chunked decode: xcd = raw&7 owns 192 consecutive logical blocks;
  // logical order: i fastest (4), then c (12), then b (4 per XCD).
  int raw = blockIdx.x;
  int nid = (raw & 7) * 192 + (raw >> 3);
  int iq = nid & 3;
  int rest = nid >> 2;
  int cb = rest % 12;
  int b = rest / 12;
  int i0 = iq * 128;
  int c0 = cb * 128;
  int t0 = cb * 2;

  int tid = threadIdx.x;
  int wave = tid >> 6, lane = tid & 63;
  int mw = (wave & 1) * 64, nw = (wave >> 1) * 64;
  int l15 = lane & 15, l4 = lane >> 4;

  floatx4 acc[4][4];
#pragma unroll
  for (int mt = 0; mt < 4; ++mt)
#pragma unroll
    for (int nt = 0; nt < 4; ++nt) acc[mt][nt] = (floatx4){0.f, 0.f, 0.f, 0.f};

  const size_t bC = (size_t)b * NC;
  for (int k0 = 0; k0 < 512; k0 += 64) {
#pragma unroll
    for (int rep = 0; rep < 4; ++rep) {
      int chunk = rep * 256 + tid;       // 1024 chunks of 16B per matrix
      int r = chunk >> 3;                // row 0..127
      int s = chunk & 7;                 // 16B slot in row
      int ss = (s ^ (r & 7)) * 8;        // swizzled source k-offset (f16 units)
      __builtin_amdgcn_global_load_lds(AS1(adjH + (size_t)(i0 + r) * 512 + k0 + ss),
                                       AS3(&As[chunk * 8]), 16, 0, 0);
      __builtin_amdgcn_global_load_lds(AS1(xT + (bC + c0 + r) * 512 + k0 + ss),
                                       AS3(&Bs[chunk * 8]), 16, 0, 0);
    }
    __syncthreads();
#pragma unroll
    for (int ks = 0; ks < 2; ++ks) {
      half8 af[4], bfv[4];
#pragma unroll
      for (int mt = 0; mt < 4; ++mt) {
        int row = mw + mt * 16 + l15;
        int slot = (ks * 4 + l4) ^ (row & 7);
        af[mt] = *(const half8*)&As[row * 64 + slot * 8];
      }
#pragma unroll
      for (int nt = 0; nt < 4; ++nt) {
        int row = nw + nt * 16 + l15;
        int slot = (ks * 4 + l4) ^ (row & 7);
        bfv[nt] = *(const half8*)&Bs[row * 64 + slot * 8];
      }
#pragma unroll
      for (int mt = 0; mt < 4; ++mt)
#pragma unroll
        for (int nt = 0; nt < 4; ++nt)
          acc[mt][nt] = __builtin_amdgcn_mfma_f32_16x16x32_f16(af[mt], bfv[nt], acc[mt][nt], 0, 0, 0);
    }
    __syncthreads();
  }

  // Epilogue: two 64-row halves. h=0 -> waves 0,2 (mw=0); h=1 -> waves 1,3.
  const size_t bE = (size_t)b * N_;
  for (int h = 0; h < 2; ++h) {
#pragma unroll
    for (int it = 0; it < 4; ++it) {
      int chunk = it * 256 + tid;        // 1024 x 16B
      int row = chunk >> 4;
      int c8 = (chunk & 15) * 8;
      __builtin_amdgcn_global_load_lds(
          AS1(E0 + (bE + i0 + h * 64 + row) * NC + c0 + c8),
          AS3(&Es[chunk * 8]), 16, 0, 0);
    }
    if ((wave & 1) == h) {
#pragma unroll
      for (int mt = 0; mt < 4; ++mt)
#pragma unroll
        for (int nt = 0; nt < 4; ++nt)
#pragma unroll
          for (int r = 0; r < 4; ++r)
            accS[(mt * 16 + l4 * 4 + r) * 132 + nw + nt * 16 + l15] = acc[mt][nt][r];
    }
    __syncthreads();   // drains vmcnt: Es + accS both ready

    {
      int f = tid & 63;
      int rj = tid >> 6;
#pragma unroll
      for (int jj = 0; jj < 16; ++jj) {
        int row = rj + 4 * jj;
        int grow = i0 + h * 64 + row;
        float v0 = accS[row * 132 + f]      + (float)Es[row * 128 + f];
        float v1 = accS[row * 132 + 64 + f] + (float)Es[row * 128 + 64 + f];
        size_t o = (((size_t)(b * N_ + grow)) * T_ + t0) * FA_ + f;
        out[o] = fmaxf(v0, 0.f);
        out[o + FA_] = fmaxf(v1, 0.f);
      }
    }
    __syncthreads();   // before next h overwrites accS/Es
  }
}

extern "C" void kernel_launch(void* const* d_in, const int* in_sizes, int n_in,
                              void* d_out, int out_size, void* d_ws, size_t ws_size,
                              hipStream_t stream) {
  const float* x     = (const float*)d_in[0];
  const float* adj   = (const float*)d_in[1];
  const float* alpha = (const float*)d_in[2];
  const float* w     = (const float*)d_in[3];
  const float* d     = (const float*)d_in[4];
  const float* w2    = (const float*)d_in[5];
  const float* d2    = (const float*)d_in[6];
  float* out = (float*)d_out;
  float* ws  = (float*)d_ws;

  hipLaunchKernelGGL(pk_kernel, dim3(257), dim3(256), 0, stream,
                     adj, alpha, w, d, w2, d2, ws);
  hipLaunchKernelGGL(prep_kernel, dim3(8, B_), dim3(256), 0, stream, x, ws, out);
  hipLaunchKernelGGL(gemm_kernel, dim3(1536), dim3(256), 0, stream, ws, out);
}

// Round 5
// 357.506 us; speedup vs baseline: 1.5448x; 1.5448x over previous
//
#include <hip/hip_runtime.h>
#include <hip/hip_fp16.h>
#include <cstdint>
#include <cstddef>

#define B_  32
#define N_  512
#define T_  24
#define F_  64
#define FA_ 74
#define NC  1536   // T_*F_ columns per node-row

typedef __attribute__((ext_vector_type(8))) _Float16 half8;
typedef __attribute__((ext_vector_type(8))) unsigned short ushort8;
typedef __attribute__((ext_vector_type(4))) float floatx4;

// ws float layout:
//  [0,74)               rsW (rowsum of W)
//  [128,704)            W2 (symmetric, row-major 24x24)
//  [1536,132608)        adjH f16[512*512]  = 0.125*sig(alpha_i)*adj[i][k]
//  [132608,12715520)    xT  f16[b][c][k]   (32*1536*512)  ~48 MB
//  [12715520,25298432)  E0  f16[b][k][c]   (32*512*1536)  ~48 MB
#define WS_ADJ 1536
#define WS_XT  132608
#define WS_E0  12715520

#define AS1(p) ((const __attribute__((address_space(1))) void*)(p))
#define AS3(p) ((__attribute__((address_space(3))) void*)(p))

union h2u { _Float16 h; unsigned short u; };

// blocks 0..255: adj fp32 -> f16 scaled by 0.125*sigmoid(alpha_i);
// block 256: rsW + W2 param precompute.
__global__ __launch_bounds__(256) void pk_kernel(
    const float* __restrict__ adj, const float* __restrict__ alpha,
    const float* __restrict__ w, const float* __restrict__ d,
    const float* __restrict__ w2, const float* __restrict__ d2,
    float* __restrict__ ws) {
  int bid = blockIdx.x;
  int tid = threadIdx.x;
  if (bid < 256) {
    _Float16* adjH = (_Float16*)(ws + WS_ADJ);
    int g = (bid * 256 + tid) * 4;
    int row = g >> 9;
    float sc = 0.125f / (1.f + __expf(-alpha[row]));
    float4 v = *(const float4*)&adj[g];
    ushort4 u4; h2u cv;
    cv.h = (_Float16)(sc * v.x); u4.x = cv.u;
    cv.h = (_Float16)(sc * v.y); u4.y = cv.u;
    cv.h = (_Float16)(sc * v.z); u4.z = cv.u;
    cv.h = (_Float16)(sc * v.w); u4.w = cv.u;
    *(ushort4*)&adjH[g] = u4;
  } else {
    __shared__ float cs[FA_];
    if (tid < FA_) {
      float s = 0.f;
      for (int n = 0; n < FA_; ++n) s += w[n * FA_ + tid];
      cs[tid] = s;
    }
    __syncthreads();
    if (tid < FA_) {
      float s = 0.f;
      for (int p = 0; p < FA_; ++p) {
        float dc = fminf(fmaxf(d[p], 0.f), 1.f);
        s += w[tid * FA_ + p] * dc * cs[p];
      }
      ws[tid] = s;
    }
    for (int e = tid; e < T_ * T_; e += 256) {
      int a = e / T_, b = e % T_;
      float s = 0.f;
      for (int p = 0; p < T_; ++p) {
        float dc = fminf(fmaxf(d2[p], 0.f), 1.f);
        s += w2[a * T_ + p] * dc * w2[b * T_ + p];
      }
      ws[128 + e] = s;
    }
  }
}

// x[b][k][c] fp32 -> xT[b][c][k] f16. 64x64 tiles. grid (24, 8, 32).
// (round-2 verified version: 37 KB LDS, ~4 blocks/CU)
__global__ __launch_bounds__(256) void transpose_x_kernel(
    const float* __restrict__ x, float* __restrict__ ws) {
  _Float16* xT = (_Float16*)(ws + WS_XT);
  __shared__ float tile[64 * 65];
  int tid = threadIdx.x;
  int b = blockIdx.z;
  int c0 = blockIdx.x * 64;
  int k0 = blockIdx.y * 64;
#pragma unroll
  for (int it = 0; it < 4; ++it) {
    int g = it * 256 + tid;
    int k = g >> 4, c4 = g & 15;
    float4 v = *(const float4*)&x[((size_t)(b * N_ + k0 + k)) * NC + c0 + c4 * 4];
    tile[k * 65 + c4 * 4 + 0] = v.x;
    tile[k * 65 + c4 * 4 + 1] = v.y;
    tile[k * 65 + c4 * 4 + 2] = v.z;
    tile[k * 65 + c4 * 4 + 3] = v.w;
  }
  __syncthreads();
#pragma unroll
  for (int it = 0; it < 4; ++it) {
    int hh = it * 256 + tid;
    int c = hh >> 4, k4 = hh & 15;
    ushort4 u4; h2u cv;
    cv.h = (_Float16)tile[(k4 * 4 + 0) * 65 + c]; u4.x = cv.u;
    cv.h = (_Float16)tile[(k4 * 4 + 1) * 65 + c]; u4.y = cv.u;
    cv.h = (_Float16)tile[(k4 * 4 + 2) * 65 + c]; u4.z = cv.u;
    cv.h = (_Float16)tile[(k4 * 4 + 3) * 65 + c]; u4.w = cv.u;
    *(ushort4*)&xT[((size_t)b * NC + c0 + c) * 512 + k0 + k4 * 4] = u4;
  }
}

// E0[b][k][c] = 0.5*x + 0.25*tmix + 0.25*S*rsW[f]  (f16, natural layout);
// also writes aug channels f>=64 of out. grid 32*128 (4 nodes/block), 256 thr.
// (round-2 verified version: 40 KB LDS, high TLP)
__global__ __launch_bounds__(256) void e_kernel(
    const float* __restrict__ x, float* __restrict__ ws, float* __restrict__ out) {
  __shared__ float xs[4 * NC];            // 24576 B
  __shared__ unsigned short es[4 * NC];   // 12288 B
  __shared__ float Ss[4 * T_];
  int tid = threadIdx.x;
  int blk = blockIdx.x;
  int b = blk >> 7;
  int i0 = (blk & 127) << 2;
  const float* xb = x + (size_t)(b * N_ + i0) * NC;
#pragma unroll
  for (int it = 0; it < 6; ++it) {
    int g = it * 256 + tid;
    *(float4*)&xs[g * 4] = *(const float4*)&xb[g * 4];
  }
  __syncthreads();

  int node = tid >> 6, f = tid & 63;
  float xcol[24];
#pragma unroll
  for (int t = 0; t < 24; ++t) xcol[t] = xs[node * NC + t * 64 + f];

  // S[t] = wave-wide sum over f (lanes of this wave are exactly f 0..63)
  float S[24];
#pragma unroll
  for (int t = 0; t < 24; ++t) S[t] = xcol[t];
#pragma unroll
  for (int off = 32; off >= 1; off >>= 1) {
#pragma unroll
    for (int t = 0; t < 24; ++t) S[t] += __shfl_xor(S[t], off, 64);
  }
  if ((tid & 63) == 0) {
#pragma unroll
    for (int t = 0; t < 24; ++t) Ss[node * 24 + t] = S[t];
  }

  const float* __restrict__ W2p = ws + 128;   // uniform scalar loads
  float rsWf = ws[f];
#pragma unroll
  for (int t = 0; t < 24; ++t) {
    float a = 0.f;
#pragma unroll
    for (int tp = 0; tp < 24; ++tp) a += xcol[tp] * W2p[t * 24 + tp];
    float val = 0.5f * xcol[t] + 0.25f * S[t] * rsWf + 0.25f * a;
    h2u cv; cv.h = (_Float16)val;
    es[node * NC + t * 64 + f] = cv.u;
  }
  __syncthreads();

  // flush E0 tile: 4*1536 f16 = 12288 B = 768 float4, coalesced
  _Float16* E0 = (_Float16*)(ws + WS_E0);
  float4* dst = (float4*)(E0 + (size_t)(b * N_ + i0) * NC);
#pragma unroll
  for (int it = 0; it < 3; ++it) {
    int g = it * 256 + tid;
    dst[g] = *(float4*)&es[g * 8];
  }

  // aug channels: 4 nodes * 24 t * 10 m = 960
#pragma unroll
  for (int it = 0; it < 4; ++it) {
    int e2 = it * 256 + tid;
    if (e2 < 960) {
      int nd = e2 / 240;
      int rem = e2 - nd * 240;
      int t = rem / 10;
      int m = rem - t * 10;
      float val = 0.25f * Ss[nd * 24 + t] * ws[64 + m];
      size_t o = ((size_t)(b * N_ + i0 + nd) * T_ + t) * FA_ + 64 + m;
      out[o] = fmaxf(val, 0.f);
    }
  }
}

// MFMA GEMM: acc = (0.125*sig(a)*adj) @ x ; out = relu(acc + E0) write-once.
// 128x128 tile, K=512, BK=64 (XOR-swizzled LDS), XCD-chunked block swizzle.
// grid 1536 (= 4 i x 12 c x 32 b), 256 thr.  (round-4 verified)
__global__ __launch_bounds__(256) void gemm_kernel(
    const float* __restrict__ ws, float* __restrict__ out) {
  const _Float16* adjH = (const _Float16*)(ws + WS_ADJ);
  const _Float16* xT   = (const _Float16*)(ws + WS_XT);
  const _Float16* E0   = (const _Float16*)(ws + WS_E0);

  __shared__ __align__(16) char smem[50176];
  _Float16* As = (_Float16*)smem;
  _Float16* Bs = (_Float16*)(smem + 16384);
  float* accS = (float*)smem;
  _Float16* Es = (_Float16*)(smem + 33792);

  // XCD-chunked decode: xcd = raw&7 owns 192 consecutive logical blocks;
  // logical order: i fastest (4), then c (12), then b (4 per XCD).
  int raw = blockIdx.x;
  int nid = (raw & 7) * 192 + (raw >> 3);
  int iq = nid & 3;
  int rest = nid >> 2;
  int cb = rest % 12;
  int b = rest / 12;
  int i0 = iq * 128;
  int c0 = cb * 128;
  int t0 = cb * 2;

  int tid = threadIdx.x;
  int wave = tid >> 6, lane = tid & 63;
  int mw = (wave & 1) * 64, nw = (wave >> 1) * 64;
  int l15 = lane & 15, l4 = lane >> 4;

  floatx4 acc[4][4];
#pragma unroll
  for (int mt = 0; mt < 4; ++mt)
#pragma unroll
    for (int nt = 0; nt < 4; ++nt) acc[mt][nt] = (floatx4){0.f, 0.f, 0.f, 0.f};

  const size_t bC = (size_t)b * NC;
  for (int k0 = 0; k0 < 512; k0 += 64) {
#pragma unroll
    for (int rep = 0; rep < 4; ++rep) {
      int chunk = rep * 256 + tid;       // 1024 chunks of 16B per matrix
      int r = chunk >> 3;                // row 0..127
      int s = chunk & 7;                 // 16B slot in row
      int ss = (s ^ (r & 7)) * 8;        // swizzled source k-offset (f16 units)
      __builtin_amdgcn_global_load_lds(AS1(adjH + (size_t)(i0 + r) * 512 + k0 + ss),
                                       AS3(&As[chunk * 8]), 16, 0, 0);
      __builtin_amdgcn_global_load_lds(AS1(xT + (bC + c0 + r) * 512 + k0 + ss),
                                       AS3(&Bs[chunk * 8]), 16, 0, 0);
    }
    __syncthreads();
#pragma unroll
    for (int ks = 0; ks < 2; ++ks) {
      half8 af[4], bfv[4];
#pragma unroll
      for (int mt = 0; mt < 4; ++mt) {
        int row = mw + mt * 16 + l15;
        int slot = (ks * 4 + l4) ^ (row & 7);
        af[mt] = *(const half8*)&As[row * 64 + slot * 8];
      }
#pragma unroll
      for (int nt = 0; nt < 4; ++nt) {
        int row = nw + nt * 16 + l15;
        int slot = (ks * 4 + l4) ^ (row & 7);
        bfv[nt] = *(const half8*)&Bs[row * 64 + slot * 8];
      }
#pragma unroll
      for (int mt = 0; mt < 4; ++mt)
#pragma unroll
        for (int nt = 0; nt < 4; ++nt)
          acc[mt][nt] = __builtin_amdgcn_mfma_f32_16x16x32_f16(af[mt], bfv[nt], acc[mt][nt], 0, 0, 0);
    }
    __syncthreads();
  }

  // Epilogue: two 64-row halves. h=0 -> waves 0,2 (mw=0); h=1 -> waves 1,3.
  const size_t bE = (size_t)b * N_;
  for (int h = 0; h < 2; ++h) {
#pragma unroll
    for (int it = 0; it < 4; ++it) {
      int chunk = it * 256 + tid;        // 1024 x 16B
      int row = chunk >> 4;
      int c8 = (chunk & 15) * 8;
      __builtin_amdgcn_global_load_lds(
          AS1(E0 + (bE + i0 + h * 64 + row) * NC + c0 + c8),
          AS3(&Es[chunk * 8]), 16, 0, 0);
    }
    if ((wave & 1) == h) {
#pragma unroll
      for (int mt = 0; mt < 4; ++mt)
#pragma unroll
        for (int nt = 0; nt < 4; ++nt)
#pragma unroll
          for (int r = 0; r < 4; ++r)
            accS[(mt * 16 + l4 * 4 + r) * 132 + nw + nt * 16 + l15] = acc[mt][nt][r];
    }
    __syncthreads();   // drains vmcnt: Es + accS both ready

    {
      int f = tid & 63;
      int rj = tid >> 6;
#pragma unroll
      for (int jj = 0; jj < 16; ++jj) {
        int row = rj + 4 * jj;
        int grow = i0 + h * 64 + row;
        float v0 = accS[row * 132 + f]      + (float)Es[row * 128 + f];
        float v1 = accS[row * 132 + 64 + f] + (float)Es[row * 128 + 64 + f];
        size_t o = (((size_t)(b * N_ + grow)) * T_ + t0) * FA_ + f;
        out[o] = fmaxf(v0, 0.f);
        out[o + FA_] = fmaxf(v1, 0.f);
      }
    }
    __syncthreads();   // before next h overwrites accS/Es
  }
}

extern "C" void kernel_launch(void* const* d_in, const int* in_sizes, int n_in,
                              void* d_out, int out_size, void* d_ws, size_t ws_size,
                              hipStream_t stream) {
  const float* x     = (const float*)d_in[0];
  const float* adj   = (const float*)d_in[1];
  const float* alpha = (const float*)d_in[2];
  const float* w     = (const float*)d_in[3];
  const float* d     = (const float*)d_in[4];
  const float* w2    = (const float*)d_in[5];
  const float* d2    = (const float*)d_in[6];
  float* out = (float*)d_out;
  float* ws  = (float*)d_ws;

  hipLaunchKernelGGL(pk_kernel, dim3(257), dim3(256), 0, stream,
                     adj, alpha, w, d, w2, d2, ws);
  hipLaunchKernelGGL(transpose_x_kernel, dim3(24, 8, B_), dim3(256), 0, stream, x, ws);
  hipLaunchKernelGGL(e_kernel, dim3(B_ * (N_ / 4)), dim3(256), 0, stream, x, ws, out);
  hipLaunchKernelGGL(gemm_kernel, dim3(1536), dim3(256), 0, stream, ws, out);
}

// Round 6
// 318.084 us; speedup vs baseline: 1.7363x; 1.1239x over previous
//
#include <hip/hip_runtime.h>
#include <hip/hip_fp16.h>
#include <cstdint>
#include <cstddef>

#define B_  32
#define N_  512
#define T_  24
#define F_  64
#define FA_ 74
#define NC  1536   // T_*F_ columns per node-row

typedef __attribute__((ext_vector_type(8))) _Float16 half8;
typedef __attribute__((ext_vector_type(8))) unsigned short ushort8;
typedef __attribute__((ext_vector_type(4))) float floatx4;

// ws float layout:
//  [0,74)               rsW (rowsum of W)
//  [128,704)            W2 (symmetric, row-major 24x24)
//  [1536,132608)        adjH f16[512*512]  = 0.125*sig(alpha_i)*adj[i][k]
//  [132608,12715520)    xT  f16[b][c][k]   (32*1536*512)  ~48 MB
#define WS_ADJ 1536
#define WS_XT  132608

#define AS1(p) ((const __attribute__((address_space(1))) void*)(p))
#define AS3(p) ((__attribute__((address_space(3))) void*)(p))

union h2u { _Float16 h; unsigned short u; };

// One dispatch, 3 block types:
//  [0,6144)    x[b][k][c] fp32 -> xT[b][c][k] f16 (64x64 tiles)
//  [6144,6400) adj fp32 -> f16 scaled by 0.125*sigmoid(alpha_i)
//  [6400]      rsW + W2 param precompute
__global__ __launch_bounds__(256) void prep_kernel(
    const float* __restrict__ x, const float* __restrict__ adj,
    const float* __restrict__ alpha, const float* __restrict__ w,
    const float* __restrict__ d, const float* __restrict__ w2,
    const float* __restrict__ d2, float* __restrict__ ws) {
  __shared__ float tile[64 * 65];
  __shared__ float cs[FA_];
  int bid = blockIdx.x;
  int tid = threadIdx.x;
  if (bid < 6144) {
    _Float16* xT = (_Float16*)(ws + WS_XT);
    int ct = bid % 24;
    int kt = (bid / 24) % 8;
    int b = bid / 192;
    int c0 = ct * 64;
    int k0 = kt * 64;
#pragma unroll
    for (int it = 0; it < 4; ++it) {
      int g = it * 256 + tid;
      int k = g >> 4, c4 = g & 15;
      float4 v = *(const float4*)&x[((size_t)(b * N_ + k0 + k)) * NC + c0 + c4 * 4];
      tile[k * 65 + c4 * 4 + 0] = v.x;
      tile[k * 65 + c4 * 4 + 1] = v.y;
      tile[k * 65 + c4 * 4 + 2] = v.z;
      tile[k * 65 + c4 * 4 + 3] = v.w;
    }
    __syncthreads();
#pragma unroll
    for (int it = 0; it < 4; ++it) {
      int hh = it * 256 + tid;
      int c = hh >> 4, k4 = hh & 15;
      ushort4 u4; h2u cv;
      cv.h = (_Float16)tile[(k4 * 4 + 0) * 65 + c]; u4.x = cv.u;
      cv.h = (_Float16)tile[(k4 * 4 + 1) * 65 + c]; u4.y = cv.u;
      cv.h = (_Float16)tile[(k4 * 4 + 2) * 65 + c]; u4.z = cv.u;
      cv.h = (_Float16)tile[(k4 * 4 + 3) * 65 + c]; u4.w = cv.u;
      *(ushort4*)&xT[((size_t)b * NC + c0 + c) * 512 + k0 + k4 * 4] = u4;
    }
  } else if (bid < 6400) {
    _Float16* adjH = (_Float16*)(ws + WS_ADJ);
    int g = ((bid - 6144) * 256 + tid) * 4;
    int row = g >> 9;
    float sc = 0.125f / (1.f + __expf(-alpha[row]));
    float4 v = *(const float4*)&adj[g];
    ushort4 u4; h2u cv;
    cv.h = (_Float16)(sc * v.x); u4.x = cv.u;
    cv.h = (_Float16)(sc * v.y); u4.y = cv.u;
    cv.h = (_Float16)(sc * v.z); u4.z = cv.u;
    cv.h = (_Float16)(sc * v.w); u4.w = cv.u;
    *(ushort4*)&adjH[g] = u4;
  } else {
    if (tid < FA_) {
      float s = 0.f;
      for (int n = 0; n < FA_; ++n) s += w[n * FA_ + tid];
      cs[tid] = s;
    }
    __syncthreads();
    if (tid < FA_) {
      float s = 0.f;
      for (int p = 0; p < FA_; ++p) {
        float dc = fminf(fmaxf(d[p], 0.f), 1.f);
        s += w[tid * FA_ + p] * dc * cs[p];
      }
      ws[tid] = s;
    }
    for (int e = tid; e < T_ * T_; e += 256) {
      int a = e / T_, b = e % T_;
      float s = 0.f;
      for (int p = 0; p < T_; ++p) {
        float dc = fminf(fmaxf(d2[p], 0.f), 1.f);
        s += w2[a * T_ + p] * dc * w2[b * T_ + p];
      }
      ws[128 + e] = s;
    }
  }
}

// MFMA GEMM + fully-fused epilogue:
//   acc = (0.125*sig(a)*adj) @ x  (f16 MFMA, 128x128 tile, K=512, BK=64)
//   out = relu(acc + 0.5*x + 0.25*tmix(x) + 0.25*S*rsW[f])  computed from
//   natural-layout fp32 x (coalesced 256B wave-loads, L2/L3-served), plus
//   aug channels f>=64. Write-once. grid 1536 (XCD-chunked), 256 thr.
__global__ __launch_bounds__(256) void gemm_kernel(
    const float* __restrict__ ws, const float* __restrict__ x,
    float* __restrict__ out) {
  const _Float16* adjH = (const _Float16*)(ws + WS_ADJ);
  const _Float16* xT   = (const _Float16*)(ws + WS_XT);

  // smem: main loop As[0,16384) Bs[16384,32768); epilogue accS fp32 64x132
  __shared__ __align__(16) char smem[33792];
  _Float16* As = (_Float16*)smem;
  _Float16* Bs = (_Float16*)(smem + 16384);
  float* accS = (float*)smem;
  __shared__ float coefs[48];

  // XCD-chunked decode: xcd = raw&7 owns 192 consecutive logical blocks;
  // logical order: i fastest (4), then c (12), then b (4 per XCD).
  int raw = blockIdx.x;
  int nid = (raw & 7) * 192 + (raw >> 3);
  int iq = nid & 3;
  int rest = nid >> 2;
  int cb = rest % 12;
  int b = rest / 12;
  int i0 = iq * 128;
  int c0 = cb * 128;
  int t0 = cb * 2;

  int tid = threadIdx.x;
  int wave = tid >> 6, lane = tid & 63;
  int mw = (wave & 1) * 64, nw = (wave >> 1) * 64;
  int l15 = lane & 15, l4 = lane >> 4;

  // tmix coefficients: 0.25*W2[t0+tl][tp] + 0.5 at tp==t (folds 0.5*x term)
  if (tid < 48) {
    int tl = tid / 24, tp = tid - (tid / 24) * 24;
    float cf = 0.25f * ws[128 + (t0 + tl) * 24 + tp];
    if (tp == t0 + tl) cf += 0.5f;
    coefs[tid] = cf;
  }

  floatx4 acc[4][4];
#pragma unroll
  for (int mt = 0; mt < 4; ++mt)
#pragma unroll
    for (int nt = 0; nt < 4; ++nt) acc[mt][nt] = (floatx4){0.f, 0.f, 0.f, 0.f};

  const size_t bC = (size_t)b * NC;
  for (int k0 = 0; k0 < 512; k0 += 64) {
#pragma unroll
    for (int rep = 0; rep < 4; ++rep) {
      int chunk = rep * 256 + tid;       // 1024 chunks of 16B per matrix
      int r = chunk >> 3;                // row 0..127
      int s = chunk & 7;                 // 16B slot in row
      int ss = (s ^ (r & 7)) * 8;        // swizzled source k-offset (f16 units)
      __builtin_amdgcn_global_load_lds(AS1(adjH + (size_t)(i0 + r) * 512 + k0 + ss),
                                       AS3(&As[chunk * 8]), 16, 0, 0);
      __builtin_amdgcn_global_load_lds(AS1(xT + (bC + c0 + r) * 512 + k0 + ss),
                                       AS3(&Bs[chunk * 8]), 16, 0, 0);
    }
    __syncthreads();
#pragma unroll
    for (int ks = 0; ks < 2; ++ks) {
      half8 af[4], bfv[4];
#pragma unroll
      for (int mt = 0; mt < 4; ++mt) {
        int row = mw + mt * 16 + l15;
        int slot = (ks * 4 + l4) ^ (row & 7);
        af[mt] = *(const half8*)&As[row * 64 + slot * 8];
      }
#pragma unroll
      for (int nt = 0; nt < 4; ++nt) {
        int row = nw + nt * 16 + l15;
        int slot = (ks * 4 + l4) ^ (row & 7);
        bfv[nt] = *(const half8*)&Bs[row * 64 + slot * 8];
      }
#pragma unroll
      for (int mt = 0; mt < 4; ++mt)
#pragma unroll
        for (int nt = 0; nt < 4; ++nt)
          acc[mt][nt] = __builtin_amdgcn_mfma_f32_16x16x32_f16(af[mt], bfv[nt], acc[mt][nt], 0, 0, 0);
    }
    __syncthreads();
  }

  // Epilogue: two 64-row halves. h=0 -> waves 0,2 (mw=0); h=1 -> waves 1,3.
  const size_t bN = (size_t)b * N_;
  int f = tid & 63;
  int rj = tid >> 6;
  float rsWf = ws[f];
  float rsWa = (f < 10) ? ws[64 + f] : 0.f;
  for (int h = 0; h < 2; ++h) {
    if ((wave & 1) == h) {
#pragma unroll
      for (int mt = 0; mt < 4; ++mt)
#pragma unroll
        for (int nt = 0; nt < 4; ++nt)
#pragma unroll
          for (int r = 0; r < 4; ++r)
            accS[(mt * 16 + l4 * 4 + r) * 132 + nw + nt * 16 + l15] = acc[mt][nt][r];
    }
    __syncthreads();

#pragma unroll 2
    for (int jj = 0; jj < 16; ++jj) {
      int row = rj + 4 * jj;
      int grow = i0 + h * 64 + row;
      const float* xr = x + (bN + grow) * NC;
      float xv[24];
#pragma unroll
      for (int tp = 0; tp < 24; ++tp) xv[tp] = xr[tp * 64 + f];  // 256B/wave
      // S[t0], S[t0+1]: wave-wide sum over f (lanes are exactly f 0..63)
      float s0 = xv[t0], s1 = xv[t0 + 1];
#pragma unroll
      for (int off = 32; off >= 1; off >>= 1) {
        s0 += __shfl_xor(s0, off, 64);
        s1 += __shfl_xor(s1, off, 64);
      }
      float tm0 = 0.f, tm1 = 0.f;
#pragma unroll
      for (int tp = 0; tp < 24; ++tp) {
        tm0 += coefs[tp] * xv[tp];
        tm1 += coefs[24 + tp] * xv[tp];
      }
      float v0 = accS[row * 132 + f]      + tm0 + 0.25f * s0 * rsWf;
      float v1 = accS[row * 132 + 64 + f] + tm1 + 0.25f * s1 * rsWf;
      size_t o = ((bN + grow) * T_ + t0) * FA_ + f;
      out[o] = fmaxf(v0, 0.f);
      out[o + FA_] = fmaxf(v1, 0.f);
      if (f < 10) {   // aug channel m == f: addr is o + 64 (since o ends in +f)
        out[o + 64] = fmaxf(0.25f * s0 * rsWa, 0.f);
        out[o + FA_ + 64] = fmaxf(0.25f * s1 * rsWa, 0.f);
      }
    }
    __syncthreads();   // before next h overwrites accS
  }
}

extern "C" void kernel_launch(void* const* d_in, const int* in_sizes, int n_in,
                              void* d_out, int out_size, void* d_ws, size_t ws_size,
                              hipStream_t stream) {
  const float* x     = (const float*)d_in[0];
  const float* adj   = (const float*)d_in[1];
  const float* alpha = (const float*)d_in[2];
  const float* w     = (const float*)d_in[3];
  const float* d     = (const float*)d_in[4];
  const float* w2    = (const float*)d_in[5];
  const float* d2    = (const float*)d_in[6];
  float* out = (float*)d_out;
  float* ws  = (float*)d_ws;

  hipLaunchKernelGGL(prep_kernel, dim3(6401), dim3(256), 0, stream,
                     x, adj, alpha, w, d, w2, d2, ws);
  hipLaunchKernelGGL(gemm_kernel, dim3(1536), dim3(256), 0, stream, ws, x, out);
}